// Round 4
// baseline (230.420 us; speedup 1.0000x reference)
//
#include <hip/hip_runtime.h>
#include <math.h>

#define NB 64
#define NS 512
#define NH 1024
#define NK 7
#define NCHUNK 16
#define CLEN 32   // NS / NCHUNK

// ---------------------------------------------------------------------------
// Fused kernel: block (b,c) stages W (28 KB) into LDS with coalesced float4
// loads, each thread pulls its 112-float fragment from LDS (ds_read_b128),
// computes emissions for its 32 rows (4 waves x 8 rows), stores them to
// LDS + global, then wave 0 folds the 32 transition matrices
// M_t[j,k] = trans[j,k] + em_t[k] in the log-semiring (31 sequential steps)
// and writes the 7x7 chunk product.
// ---------------------------------------------------------------------------
__global__ __launch_bounds__(256) void fused_emis_chunk(
    const float* __restrict__ x, const float* __restrict__ W,
    const float* __restrict__ bias, const float* __restrict__ trans,
    float* __restrict__ em, float* __restrict__ chunkP)
{
    __shared__ float lds_W[NH * NK];     // 28672 B, coalesced-staged
    __shared__ float lds_em[CLEN * 8];
    __shared__ float lds_tr[49];

    const int lane = threadIdx.x & 63;
    const int wave = threadIdx.x >> 6;
    const int b = blockIdx.x >> 4;
    const int c = blockIdx.x & (NCHUNK - 1);
    const int t0 = c * CLEN;
    const int row0 = b * NS + t0;

    // ---- coalesced W -> LDS (1792 float4, 7 per thread) ----------------
    {
        const float4* W4 = (const float4*)W;
        float4* L4 = (float4*)lds_W;
#pragma unroll
        for (int i = 0; i < (NH * NK / 4) / 256; ++i)
            L4[threadIdx.x + 256 * i] = W4[threadIdx.x + 256 * i];
    }
    if (threadIdx.x < 49) lds_tr[threadIdx.x] = trans[threadIdx.x];
    __syncthreads();

    // ---- fragment from LDS: frag[cc][i*7+k] = W[4*(cc*64+lane)+i][k] ---
    float frag[4][28];
#pragma unroll
    for (int cc = 0; cc < 4; ++cc) {
        const float4* src = (const float4*)(lds_W + 28 * (cc * 64 + lane));
        float4* dst = (float4*)frag[cc];
#pragma unroll
        for (int q = 0; q < 7; ++q) dst[q] = src[q];
    }
    const float bl = bias[lane < NK ? lane : 0];

    for (int r = wave; r < CLEN; r += 4) {
        const float4* xr = (const float4*)(x + (size_t)(row0 + r) * NH);
        float acc[NK];
#pragma unroll
        for (int k = 0; k < NK; ++k) acc[k] = 0.f;
#pragma unroll
        for (int cc = 0; cc < 4; ++cc) {
            const float4 v = xr[cc * 64 + lane];
#pragma unroll
            for (int k = 0; k < NK; ++k)
                acc[k] += v.x * frag[cc][k]      + v.y * frag[cc][7 + k]
                        + v.z * frag[cc][14 + k] + v.w * frag[cc][21 + k];
        }
        // 3 butterfly levels within groups of 8 lanes
#pragma unroll
        for (int m = 1; m < 8; m <<= 1)
#pragma unroll
            for (int k = 0; k < NK; ++k)
                acc[k] += __shfl_xor(acc[k], m, 64);
        // select acc[lane&7]
        const int s = lane & 7;
        const float v01 = (s & 1) ? acc[1] : acc[0];
        const float v23 = (s & 1) ? acc[3] : acc[2];
        const float v45 = (s & 1) ? acc[5] : acc[4];
        const float w03 = (s & 2) ? v23 : v01;
        const float w47 = (s & 2) ? acc[6] : v45;
        float v = (s & 4) ? w47 : w03;
        v += __shfl_xor(v, 8, 64);
        v += __shfl_xor(v, 16, 64);
        v += __shfl_xor(v, 32, 64);
        if (lane < NK) {
            const float e = v + bl;
            lds_em[r * 8 + lane] = e;
            em[(size_t)(row0 + r) * NK + lane] = e;
        }
    }
    __syncthreads();
    if (wave != 0) return;

    // ---- chunk scan on wave 0 (lane = i*7+k, 49 active) ----------------
    const int li = lane < 49 ? lane : 48;
    const int i = li / 7;
    const int k = li - i * 7;
    float tj[NK];
#pragma unroll
    for (int j = 0; j < NK; ++j) tj[j] = lds_tr[j * 7 + k];

    const int first = (c == 0) ? 1 : 0;   // chunk 0 covers t=1..31
    float P = lds_tr[i * 7 + k] + lds_em[first * 8 + k];
    for (int t = first + 1; t < CLEN; ++t) {
        float a[NK];
#pragma unroll
        for (int j = 0; j < NK; ++j)
            a[j] = __shfl(P, i * 7 + j, 64) + tj[j];
        const float m = fmaxf(fmaxf(fmaxf(a[0], a[1]), fmaxf(a[2], a[3])),
                              fmaxf(fmaxf(a[4], a[5]), a[6]));
        const float su = __expf(a[0]-m) + __expf(a[1]-m) + __expf(a[2]-m)
                       + __expf(a[3]-m) + __expf(a[4]-m) + __expf(a[5]-m)
                       + __expf(a[6]-m);
        P = m + __logf(su) + lds_em[t * 8 + k];
    }
    if (lane < 49)
        chunkP[(size_t)(b * NCHUNK + c) * 49 + lane] = P;
}

// ---------------------------------------------------------------------------
// Combine: per-batch numerator + 16 log-semiring matvecs + denominator,
// atomic mean into out[0] (out pre-zeroed by hipMemsetAsync).
// ---------------------------------------------------------------------------
__global__ __launch_bounds__(64) void combine_kernel(
    const float* __restrict__ em, const float* __restrict__ chunkP,
    const int* __restrict__ gt32,
    const float* __restrict__ start_trans, const float* __restrict__ end_trans,
    const float* __restrict__ trans, float* __restrict__ out)
{
    __shared__ float lds_C[NCHUNK * 49];
    __shared__ float lds_tr[49];
    __shared__ int   lds_gt[NS];
    const int b    = blockIdx.x;
    const int lane = threadIdx.x;

    // detect int64 gt encoding (reference dtype is int64)
    int oddbits = 0;
    for (int i = lane; i < 256; i += 64) oddbits |= gt32[2 * i + 1];
    const bool is64 = (__ballot(oddbits != 0) == 0ull);

    for (int idx = lane; idx < NCHUNK * 49; idx += 64)
        lds_C[idx] = chunkP[(size_t)b * NCHUNK * 49 + idx];
    for (int i = lane; i < NS; i += 64) {
        const int gidx = b * NS + i;
        lds_gt[i] = is64 ? gt32[2 * gidx] : gt32[gidx];
    }
    if (lane < 49) lds_tr[lane] = trans[lane];
    __syncthreads();

    // ---- numerator -----------------------------------------------------
    const float* emb = em + (size_t)b * NS * NK;
    float numpart = 0.f;
#pragma unroll
    for (int ii = 0; ii < NS / 64; ++ii) {
        const int t = lane + 64 * ii;
        const int g = lds_gt[t];
        if (t == 0) numpart += start_trans[g] + emb[g];
        else        numpart += lds_tr[lds_gt[t - 1] * 7 + g] + emb[t * NK + g];
    }
#pragma unroll
    for (int m = 1; m < 64; m <<= 1) numpart += __shfl_xor(numpart, m, 64);
    const float num = numpart + end_trans[lds_gt[NS - 1]];

    // ---- alpha chain: alpha0 then 16 matvecs ---------------------------
    const int kk = lane < NK ? lane : NK - 1;
    float alpha = start_trans[kk] + emb[kk];
#pragma unroll
    for (int c = 0; c < NCHUNK; ++c) {
        float a[NK];
#pragma unroll
        for (int j = 0; j < NK; ++j)
            a[j] = __shfl(alpha, j, 64) + lds_C[c * 49 + j * 7 + kk];
        const float m = fmaxf(fmaxf(fmaxf(a[0], a[1]), fmaxf(a[2], a[3])),
                              fmaxf(fmaxf(a[4], a[5]), a[6]));
        const float su = __expf(a[0]-m) + __expf(a[1]-m) + __expf(a[2]-m)
                       + __expf(a[3]-m) + __expf(a[4]-m) + __expf(a[5]-m)
                       + __expf(a[6]-m);
        alpha = m + __logf(su);
    }

    // ---- denominator LSE over k + atomic mean --------------------------
    float v = (lane < NK) ? (alpha + end_trans[kk]) : -3.0e38f;
    float mv = v;
#pragma unroll
    for (int m = 1; m < 8; m <<= 1) mv = fmaxf(mv, __shfl_xor(mv, m, 64));
    float e = (lane < NK) ? __expf(v - mv) : 0.f;
#pragma unroll
    for (int m = 1; m < 8; m <<= 1) e += __shfl_xor(e, m, 64);
    if (lane == 0)
        atomicAdd(out, ((mv + __logf(e)) - num) * (1.0f / NB));
}

extern "C" void kernel_launch(void* const* d_in, const int* in_sizes, int n_in,
                              void* d_out, int out_size, void* d_ws, size_t ws_size,
                              hipStream_t stream)
{
    const float* x    = (const float*)d_in[0];
    const int*   gt   = (const int*)d_in[1];
    // d_in[2] = mask: all ones by construction — unused.
    const float* W    = (const float*)d_in[3];
    const float* bias = (const float*)d_in[4];
    const float* st   = (const float*)d_in[5];
    const float* et   = (const float*)d_in[6];
    const float* tr   = (const float*)d_in[7];

    float* em     = (float*)d_ws;                          // NB*NS*NK
    float* chunkP = em + (size_t)NB * NS * NK;             // NB*NCHUNK*49

    hipMemsetAsync(d_out, 0, sizeof(float) * out_size, stream);
    fused_emis_chunk<<<NB * NCHUNK, 256, 0, stream>>>(x, W, bias, tr, em, chunkP);
    combine_kernel<<<NB, 64, 0, stream>>>(em, chunkP, gt, st, et, tr, (float*)d_out);
}